// Round 1
// baseline (348.955 us; speedup 1.0000x reference)
//
#include <hip/hip_runtime.h>
#include <hip/hip_bf16.h>

// ConformerAttention on MI355X (gfx950), bf16 MFMA internal, fp32 in/out.
// rel_shift(ps)[i,j] == ps[i, j-i+S-1]  -> banded pos-score, never materialize [S,P].

typedef __attribute__((ext_vector_type(8))) short  s16x8;
typedef __attribute__((ext_vector_type(8))) __bf16 bfv8;
typedef __attribute__((ext_vector_type(4))) float  f32x4;

__device__ __forceinline__ float b2f(short s){
  unsigned u = ((unsigned)(unsigned short)s) << 16;
  float f; __builtin_memcpy(&f, &u, 4); return f;
}
__device__ __forceinline__ short f2b(float f){
  unsigned u; __builtin_memcpy(&u, &f, 4);
  u = (u + 0x7fffu + ((u >> 16) & 1u)) >> 16;
  return (short)u;
}
__device__ __forceinline__ f32x4 MFMA(s16x8 a, s16x8 b, f32x4 c){
  return __builtin_amdgcn_mfma_f32_16x16x32_bf16(
      __builtin_bit_cast(bfv8, a), __builtin_bit_cast(bfv8, b), c, 0, 0, 0);
}
__device__ __forceinline__ void gload_lds16(const void* g, void* l){
  __builtin_amdgcn_global_load_lds(
      (const __attribute__((address_space(1))) void*)g,
      (__attribute__((address_space(3))) void*)l, 16, 0, 0);
}

// ---- f32 -> bf16 convert, 8 elems/thread ----
__global__ __launch_bounds__(256) void cvt_bf16(const float* __restrict__ in,
                                                short* __restrict__ out, int n8){
  int i = blockIdx.x*256 + threadIdx.x;
  if(i >= n8) return;
  f32x4 a = *(const f32x4*)(in + (size_t)i*8);
  f32x4 b = *(const f32x4*)(in + (size_t)i*8 + 4);
  short o[8];
  o[0]=f2b(a[0]); o[1]=f2b(a[1]); o[2]=f2b(a[2]); o[3]=f2b(a[3]);
  o[4]=f2b(b[0]); o[5]=f2b(b[1]); o[6]=f2b(b[2]); o[7]=f2b(b[3]);
  *(s16x8*)(out + (size_t)i*8) = *(s16x8*)o;
}

// ---- LayerNorm: one wave per row of 512, bf16 out ----
__global__ __launch_bounds__(64) void ln_kernel(const float* __restrict__ x,
    const float* __restrict__ w, const float* __restrict__ b, short* __restrict__ out){
  int row = blockIdx.x; int lane = threadIdx.x;
  const float* xr = x + (size_t)row*512;
  f32x4 v0 = *(const f32x4*)(xr + lane*8);
  f32x4 v1 = *(const f32x4*)(xr + lane*8 + 4);
  float s  = v0[0]+v0[1]+v0[2]+v0[3]+v1[0]+v1[1]+v1[2]+v1[3];
  float s2 = v0[0]*v0[0]+v0[1]*v0[1]+v0[2]*v0[2]+v0[3]*v0[3]
           + v1[0]*v1[0]+v1[1]*v1[1]+v1[2]*v1[2]+v1[3]*v1[3];
  #pragma unroll
  for(int m=1;m<64;m<<=1){ s += __shfl_xor(s,m); s2 += __shfl_xor(s2,m); }
  float mu = s * (1.0f/512.0f);
  float rs = rsqrtf(s2*(1.0f/512.0f) - mu*mu + 1e-5f);
  short o[8];
  #pragma unroll
  for(int e=0;e<8;e++){
    float xv = (e<4)? v0[e] : v1[e-4];
    int d = lane*8 + e;
    o[e] = f2b((xv - mu)*rs*w[d] + b[d]);
  }
  *(s16x8*)(out + (size_t)row*512 + lane*8) = *(s16x8*)o;
}

// ---- GEMM: C[M,N] = A[M,K] @ B[N,K]^T (+bias) (+resid, fp32 out) ----
// 128x128 tile, BK=32, 4 waves (2x2 of 64x64), global_load_lds staging.
template<int MODE>  // 0: bf16 out (+bias), 1: fp32 out (+bias+resid)
__global__ __launch_bounds__(256) void gemm_bt(
    const short* __restrict__ A, const short* __restrict__ B,
    const float* __restrict__ bias, const float* __restrict__ resid,
    void* __restrict__ Cout, int M, int N, int K, int Aclamp)
{
  __shared__ __align__(16) short At[128*32];
  __shared__ __align__(16) short Bt[128*32];
  int tid = threadIdx.x;
  int wave = tid >> 6, lane = tid & 63;
  int quad = lane >> 4, l16 = lane & 15;
  int wm = wave >> 1, wn = wave & 1;
  int m0 = blockIdx.y*128, n0 = blockIdx.x*128;
  int srow = lane >> 2, scol = (lane & 3)*8;
  f32x4 acc[4][4] = {};
  for(int k0=0; k0<K; k0+=32){
    #pragma unroll
    for(int c=0;c<2;c++){
      int r = wave*32 + c*16 + srow;
      int ra = m0 + r; if(ra > Aclamp-1) ra = Aclamp-1;
      gload_lds16(A + (size_t)ra*K + k0 + scol, At + (wave*32 + c*16)*32);
      gload_lds16(B + (size_t)(n0 + r)*K + k0 + scol, Bt + (wave*32 + c*16)*32);
    }
    __syncthreads();
    s16x8 af[4], bfr[4];
    #pragma unroll
    for(int i=0;i<4;i++) af[i]  = *(const s16x8*)(At + (wm*64 + i*16 + l16)*32 + quad*8);
    #pragma unroll
    for(int j=0;j<4;j++) bfr[j] = *(const s16x8*)(Bt + (wn*64 + j*16 + l16)*32 + quad*8);
    #pragma unroll
    for(int i=0;i<4;i++)
      #pragma unroll
      for(int j=0;j<4;j++)
        acc[i][j] = MFMA(af[i], bfr[j], acc[i][j]);
    __syncthreads();
  }
  #pragma unroll
  for(int i=0;i<4;i++){
    int rowb = m0 + wm*64 + i*16 + quad*4;
    #pragma unroll
    for(int j=0;j<4;j++){
      int col = n0 + wn*64 + j*16 + l16;
      float bv = bias ? bias[col] : 0.0f;
      #pragma unroll
      for(int r=0;r<4;r++){
        size_t idx = (size_t)(rowb + r)*N + col;
        float v = acc[i][j][r] + bv;
        if(MODE == 0) ((short*)Cout)[idx] = f2b(v);
        else          ((float*)Cout)[idx] = v + resid[idx];
      }
    }
  }
}

// ---- Fused rel-pos attention ----
// grid(16 qtiles, 8 heads, 8 batch), 256 thr = 4 waves, 16 q-rows/wave.
// score(i,j) = [(q_i+u)·k_j + (q_i+v)·p_{j-i+1023}] / 8 ; online softmax ; O = P@V.
__global__ __launch_bounds__(256) void attn_kernel(
    const short* __restrict__ q, const short* __restrict__ k, const short* __restrict__ v,
    const short* __restrict__ p, const float* __restrict__ bu, const float* __restrict__ bvv,
    short* __restrict__ out)
{
  __shared__ __align__(16) float ps_lds[4][16*84];  // per-wave banded pos scores
  __shared__ __align__(16) short p_lds[4][16*72];   // per-wave P tile (A-layout src)
  __shared__ __align__(16) short vt_lds[64*72];     // V^T tile [d][j], shared
  int tid = threadIdx.x;
  int wave = tid >> 6, lane = tid & 63, quad = lane >> 4, l16 = lane & 15;
  int qt = blockIdx.x, h = blockIdx.y, b = blockIdx.z;
  int iw = qt*64 + wave*16;

  // q fragments with bias_u / bias_v folded in (A-layout, 2 k-steps of 32)
  size_t qbase = ((size_t)(b*1024 + iw + l16)*512) + h*64;
  s16x8 qu[2], qv[2];
  #pragma unroll
  for(int ks=0;ks<2;ks++){
    s16x8 qr = *(const s16x8*)(q + qbase + ks*32 + quad*8);
    short tu[8], tv[8];
    #pragma unroll
    for(int e=0;e<8;e++){
      int d = h*64 + ks*32 + quad*8 + e;
      float f = b2f(qr[e]);
      tu[e] = f2b(f + bu[d]);
      tv[e] = f2b(f + bvv[d]);
    }
    qu[ks] = *(s16x8*)tu; qv[ks] = *(s16x8*)tv;
  }

  f32x4 oacc[4] = {};
  float mrow[4], lrow[4];
  #pragma unroll
  for(int r=0;r<4;r++){ mrow[r] = -1e30f; lrow[r] = 0.0f; }
  float* psw = ps_lds[wave];
  short* pw  = p_lds[wave];

  for(int jt=0; jt<16; jt++){
    int j0 = jt*64;
    // stage V^T [64 d][64 j] (row stride 72)
    #pragma unroll
    for(int it=0; it<2; it++){
      int c = tid + it*256;
      int jl = c >> 3, dch = c & 7;
      s16x8 vv = *(const s16x8*)(v + ((size_t)(b*1024 + j0 + jl)*512) + h*64 + dch*8);
      #pragma unroll
      for(int e=0;e<8;e++) vt_lds[(dch*8+e)*72 + jl] = vv[e];
    }
    __syncthreads();

    // content scores: 4 j-subtiles x 2 k-steps
    f32x4 sc[4];
    #pragma unroll
    for(int js=0;js<4;js++){
      f32x4 a = {};
      #pragma unroll
      for(int ks=0;ks<2;ks++){
        s16x8 kf = *(const s16x8*)(k + ((size_t)(b*1024 + j0 + js*16 + l16)*512) + h*64 + ks*32 + quad*8);
        a = MFMA(qu[ks], kf, a);
      }
      sc[js] = a;
    }
    // banded pos scores: r window [r0, r0+79], r0 in [0,1968], reads < 2048 (padded p)
    int r0 = j0 - iw + 1008;
    #pragma unroll
    for(int nt=0;nt<5;nt++){
      f32x4 a = {};
      #pragma unroll
      for(int ks=0;ks<2;ks++){
        s16x8 pf = *(const s16x8*)(p + ((size_t)(r0 + nt*16 + l16)*512) + h*64 + ks*32 + quad*8);
        a = MFMA(qv[ks], pf, a);
      }
      #pragma unroll
      for(int r=0;r<4;r++) psw[(quad*4+r)*84 + nt*16 + l16] = a[r];
    }
    __syncthreads();

    // gather band (r_local = jl - il + 15), combine, online softmax
    float pvals[4][4];
    #pragma unroll
    for(int r=0;r<4;r++){
      int il = quad*4 + r;
      float mx = -1e30f;
      #pragma unroll
      for(int js=0;js<4;js++){
        int jl = js*16 + l16;
        float sv = (sc[js][r] + psw[il*84 + (jl - il + 15)]) * 0.125f;
        pvals[js][r] = sv;
        mx = fmaxf(mx, sv);
      }
      #pragma unroll
      for(int m=1;m<16;m<<=1) mx = fmaxf(mx, __shfl_xor(mx, m));
      float mn = fmaxf(mrow[r], mx);
      float alpha = __expf(mrow[r] - mn);
      mrow[r] = mn;
      float ls = 0.0f;
      #pragma unroll
      for(int js=0;js<4;js++){
        float pe = __expf(pvals[js][r] - mn);
        pvals[js][r] = pe;
        ls += pe;
      }
      #pragma unroll
      for(int m=1;m<16;m<<=1) ls += __shfl_xor(ls, m);
      lrow[r] = lrow[r]*alpha + ls;
      #pragma unroll
      for(int ds=0;ds<4;ds++) oacc[ds][r] *= alpha;
    }
    // P -> LDS in PV A-layout source form
    #pragma unroll
    for(int js=0;js<4;js++)
      #pragma unroll
      for(int r=0;r<4;r++)
        pw[(quad*4+r)*72 + js*16 + l16] = f2b(pvals[js][r]);
    __syncthreads();

    // PV: 2 j-ksteps x 4 d-subtiles
    #pragma unroll
    for(int jk=0;jk<2;jk++){
      s16x8 pf = *(const s16x8*)(pw + l16*72 + jk*32 + quad*8);
      #pragma unroll
      for(int ds=0;ds<4;ds++){
        s16x8 vf = *(const s16x8*)(vt_lds + (ds*16 + l16)*72 + jk*32 + quad*8);
        oacc[ds] = MFMA(pf, vf, oacc[ds]);
      }
    }
    __syncthreads();
  }
  // epilogue: normalize, write bf16 [B,S,H,hd] == [8192,512]
  #pragma unroll
  for(int ds=0; ds<4; ds++){
    #pragma unroll
    for(int r=0;r<4;r++){
      int il = quad*4 + r;
      float ov = oacc[ds][r] / lrow[r];
      out[((size_t)(b*1024 + iw + il)*512) + h*64 + ds*16 + l16] = f2b(ov);
    }
  }
}

extern "C" void kernel_launch(void* const* d_in, const int* in_sizes, int n_in,
                              void* d_out, int out_size, void* d_ws, size_t ws_size,
                              hipStream_t stream)
{
  const float* x    = (const float*)d_in[0];
  const float* pos  = (const float*)d_in[1];
  const float* lnw  = (const float*)d_in[2];
  const float* lnb  = (const float*)d_in[3];
  const float* Wq   = (const float*)d_in[4];
  const float* bq   = (const float*)d_in[5];
  const float* Wk   = (const float*)d_in[6];
  const float* bk   = (const float*)d_in[7];
  const float* Wv   = (const float*)d_in[8];
  const float* bv   = (const float*)d_in[9];
  const float* Wo   = (const float*)d_in[10];
  const float* bo   = (const float*)d_in[11];
  const float* Wp   = (const float*)d_in[12];
  const float* pbu  = (const float*)d_in[13];
  const float* pbv  = (const float*)d_in[14];
  float* out = (float*)d_out;

  char* ws = (char*)d_ws;
  short* h_bf   = (short*)(ws);                       // 8192x512
  short* q_bf   = (short*)(ws + ( 8u<<20));
  short* k_bf   = (short*)(ws + (16u<<20));
  short* v_bf   = (short*)(ws + (24u<<20));
  short* a_bf   = (short*)(ws + (32u<<20));
  short* p_bf   = (short*)(ws + (40u<<20));           // 2048x512 (padded)
  short* pos_bf = (short*)(ws + (42u<<20));           // 2047x512
  short* wq_bf  = (short*)(ws + (44u<<20));
  short* wk_bf  = (short*)(ws + (45u<<20));
  short* wv_bf  = (short*)(ws + (46u<<20));
  short* wo_bf  = (short*)(ws + (47u<<20));
  short* wp_bf  = (short*)(ws + (48u<<20));

  // weight / pos_emb converts
  cvt_bf16<<<dim3(128), 256, 0, stream>>>(Wq, wq_bf, 512*512/8);
  cvt_bf16<<<dim3(128), 256, 0, stream>>>(Wk, wk_bf, 512*512/8);
  cvt_bf16<<<dim3(128), 256, 0, stream>>>(Wv, wv_bf, 512*512/8);
  cvt_bf16<<<dim3(128), 256, 0, stream>>>(Wo, wo_bf, 512*512/8);
  cvt_bf16<<<dim3(128), 256, 0, stream>>>(Wp, wp_bf, 512*512/8);
  cvt_bf16<<<dim3(512), 256, 0, stream>>>(pos, pos_bf, 2047*512/8);
  // LayerNorm
  ln_kernel<<<dim3(8192), 64, 0, stream>>>(x, lnw, lnb, h_bf);
  // projections
  gemm_bt<0><<<dim3(4,64), 256, 0, stream>>>(h_bf, wq_bf, bq, nullptr, q_bf, 8192,512,512, 8192);
  gemm_bt<0><<<dim3(4,64), 256, 0, stream>>>(h_bf, wk_bf, bk, nullptr, k_bf, 8192,512,512, 8192);
  gemm_bt<0><<<dim3(4,64), 256, 0, stream>>>(h_bf, wv_bf, bv, nullptr, v_bf, 8192,512,512, 8192);
  gemm_bt<0><<<dim3(4,16), 256, 0, stream>>>(pos_bf, wp_bf, nullptr, nullptr, p_bf, 2048,512,512, 2047);
  // fused attention
  attn_kernel<<<dim3(16,8,8), 256, 0, stream>>>(q_bf, k_bf, v_bf, p_bf, pbu, pbv, a_bf);
  // output projection + bias + residual
  gemm_bt<1><<<dim3(4,64), 256, 0, stream>>>(a_bf, wo_bf, bo, x, out, 8192,512,512, 8192);
  (void)in_sizes; (void)n_in; (void)out_size; (void)ws_size;
}